// Round 1
// baseline (1645.565 us; speedup 1.0000x reference)
//
#include <hip/hip_runtime.h>

// SNN: T=200, B=256, IN=784, N=1024, OUT=10
// W_rec = -0.5*(ones - I) => prev@W_rec = -0.5*(S_b - prev[b,j])  (exact in
// fp32: all partial sums are multiples of 0.5 with |.| <= 512).
// net_in[t] = x_t @ W_in is time-independent => one big fp32 GEMM up front
// into d_out's hidden_spikes region, then an in-place spike scan.
//
// NUMERICS CONTRACT: dynamics are knife-edge (absmax 512 of 611 = one
// marginal spike-step flip vs BLAS summation order). The GEMM keeps a single
// ascending-k fmaf chain per output element — bit-identical across rounds.
// No MFMA/bf16, no split-K, no reassociation, true division in the scan.

#define TT 200
#define BB 256
#define KK 784
#define NN 1024
#define OO 10

// ---------------- Phase 1: net = X(51200x784) @ W(784x1024), fp32 ----------
// 128x128 tile, BK=16, 256 threads, 8x8 micro-tile (2x2 quadrants of 4x4).
// v2: LDS DOUBLE-BUFFER — one lgkm-only barrier per tile (was 2 full
// __syncthreads, each an implicit vmcnt(0) drain that killed the prefetch).
// Pipeline per tile: ds_write regs(t+1)->buf[nxt], issue global loads (t+2),
// 1024 FMAs on buf[cur], lgkm-barrier. Global loads stay in flight across
// the barrier (vmcnt NOT drained); __launch_bounds__(256,4) gives a 128-VGPR
// budget so the 16 prefetch regs stay live across the FMA block (the old
// build allocated exactly 80 = 64 acc + 16 frag: prefetch was being sunk).
__global__ __launch_bounds__(256, 4)
void gemm_net(const float* __restrict__ X, const float* __restrict__ W,
              float* __restrict__ C) {
  __shared__ float As[2][16][128];   // [buf][k][m] (A staged transposed)
  __shared__ float Bs[2][16][128];   // [buf][k][n]

  const int tid = threadIdx.x;
  const int n0 = blockIdx.x * 128;
  const int m0 = blockIdx.y * 128;
  const int tx = tid & 15;             // cols tx*4, 64+tx*4
  const int ty = tid >> 4;             // rows ty*4, 64+ty*4
  const int arow = tid >> 1;           // 0..127
  const int ak   = (tid & 1) * 8;      // 0 or 8
  const int brow = tid >> 5;           // 0..7 (and +8)
  const int bc   = (tid & 31) * 4;     // 0..124

  const float* ap = X + (size_t)(m0 + arow) * KK + ak;
  const float* bp = W + (size_t)brow * NN + n0 + bc;

  // tile 0 -> regs
  float4 a0 = *(const float4*)(ap);
  float4 a1 = *(const float4*)(ap + 4);
  float4 b0 = *(const float4*)(bp);
  float4 b1 = *(const float4*)(bp + 8 * NN);

#define STAGE(q)                                                            \
  do {                                                                      \
    As[q][ak + 0][arow] = a0.x;  /* bank=arow%32, 2-way (free) */           \
    As[q][ak + 1][arow] = a0.y;                                             \
    As[q][ak + 2][arow] = a0.z;                                             \
    As[q][ak + 3][arow] = a0.w;                                             \
    As[q][ak + 4][arow] = a1.x;                                             \
    As[q][ak + 5][arow] = a1.y;                                             \
    As[q][ak + 6][arow] = a1.z;                                             \
    As[q][ak + 7][arow] = a1.w;                                             \
    *(float4*)&Bs[q][brow][bc] = b0;     /* lane-consecutive: clean */      \
    *(float4*)&Bs[q][brow + 8][bc] = b1;                                    \
  } while (0)

  // tile 0 -> LDS buf0; tile 1 -> regs
  STAGE(0);
  ap += 16;
  bp += 16 * NN;
  a0 = *(const float4*)(ap);
  a1 = *(const float4*)(ap + 4);
  b0 = *(const float4*)(bp);
  b1 = *(const float4*)(bp + 8 * NN);

  // lgkm-only barrier: buf0 writes visible; tile-1 global loads in flight.
  __asm__ volatile("s_waitcnt lgkmcnt(0)\n\ts_barrier" ::: "memory");

  float acc[2][2][4][4] = {};

  for (int k0 = 0; k0 < KK; k0 += 16) {   // 49 tiles
    const int cur = (k0 >> 4) & 1;
    if (k0 + 16 < KK) {
      const int nxt = cur ^ 1;
      STAGE(nxt);                         // regs(t+1) -> other buffer
      if (k0 + 32 < KK) {                 // issue loads for tile t+2
        ap += 16;
        bp += 16 * NN;
        a0 = *(const float4*)(ap);
        a1 = *(const float4*)(ap + 4);
        b0 = *(const float4*)(bp);
        b1 = *(const float4*)(bp + 8 * NN);
      }
    }
    const float4 (*Ac4)[32] = (const float4(*)[32])As[cur];
    const float4 (*Bc4)[32] = (const float4(*)[32])Bs[cur];
#pragma unroll
    for (int k = 0; k < 16; ++k) {
      float4 A0 = Ac4[k][ty];          // broadcast (free)
      float4 A1 = Ac4[k][16 + ty];
      float4 B0 = Bc4[k][tx];          // 2-way (free)
      float4 B1 = Bc4[k][16 + tx];
      float av[2][4] = {{A0.x, A0.y, A0.z, A0.w}, {A1.x, A1.y, A1.z, A1.w}};
      float bv[2][4] = {{B0.x, B0.y, B0.z, B0.w}, {B1.x, B1.y, B1.z, B1.w}};
#pragma unroll
      for (int qi = 0; qi < 2; ++qi)
#pragma unroll
        for (int qj = 0; qj < 2; ++qj)
#pragma unroll
          for (int i = 0; i < 4; ++i)
#pragma unroll
            for (int j = 0; j < 4; ++j)
              acc[qi][qj][i][j] =
                  fmaf(av[qi][i], bv[qj][j], acc[qi][qj][i][j]);
    }
    // end-of-tile barrier: my buf[nxt] writes visible to all before anyone
    // reads them next tile; lgkm-only so prefetch loads span the barrier.
    __asm__ volatile("s_waitcnt lgkmcnt(0)\n\ts_barrier" ::: "memory");
  }
#undef STAGE

#pragma unroll
  for (int qi = 0; qi < 2; ++qi)
#pragma unroll
    for (int i = 0; i < 4; ++i) {
      const int r = m0 + qi * 64 + ty * 4 + i;
#pragma unroll
      for (int qj = 0; qj < 2; ++qj) {
        float4 v = {acc[qi][qj][i][0], acc[qi][qj][i][1],
                    acc[qi][qj][i][2], acc[qi][qj][i][3]};
        *(float4*)(C + (size_t)r * NN + n0 + qj * 64 + tx * 4) = v;
      }
    }
}

// ---------------- Phase 2: sequential scan, one block per batch row --------
// 1024 threads (1 neuron each, 16 waves). hid holds net on entry; overwritten
// in place with spikes. One lgkm-only barrier per step (inline asm) so the
// spike stores and depth-2 net prefetch stay in flight across the barrier —
// __syncthreads' implicit vmcnt(0) drain would serialize a global-latency
// round trip into every step.  (UNCHANGED this round.)
__global__ __launch_bounds__(1024)
void snn_scan(float* __restrict__ hid, const float* __restrict__ Wout,
              float* __restrict__ logits) {
  constexpr float V_REST = -65.0f, THRESH0 = -50.0f, TAU_M = 20.0f,
                  TAU_TH = 100.0f, BETA = 5.0f, DT = 1.0f;
  const int b = blockIdx.x;
  const int tid = threadIdx.x;
  const int wave = tid >> 6, lane = tid & 63;
  __shared__ float s_part[2][16];
  __shared__ float s_log[16][OO];

  float mp = V_REST, th = THRESH0, prev = 0.0f, cnt = 0.0f;
  float S = 0.0f;
  const size_t base = (size_t)b * NN + tid;
  const size_t STEP = (size_t)BB * NN;

  // depth-2 prefetch pipeline for net
  float netc = hid[base];                 // t = 0
  float netn = hid[STEP + base];          // t = 1

  for (int t = 0; t < TT; ++t) {
    float rec = -0.5f * (S - prev);       // exact closed-form prev@W_rec
    float nv = netc + rec;                // matches np elementwise add order
    float m = mp + (V_REST - mp) / TAU_M; // true division, as reference
    m = m + nv * DT;
    bool spk = (m >= th);
    float s = spk ? 1.0f : 0.0f;
    th = (th + BETA * s) - ((th - THRESH0) / TAU_TH) * DT; // old th both terms
    mp = spk ? V_REST : m;
    cnt += s;
    prev = s;
    hid[(size_t)t * STEP + base] = s;

    // rotate prefetch: issue t+2 now (independent of this step's results)
    float netf = 0.0f;
    if (t + 2 < TT) netf = hid[(size_t)(t + 2) * STEP + base];
    netc = netn;
    netn = netf;

    // row spike count: ballot+popcount per wave; parity-buffered partials;
    // lgkm-only barrier (global loads/stores NOT drained).
    unsigned long long bal = __ballot(spk);
    if (lane == 0) s_part[t & 1][wave] = (float)__popcll(bal);
    __asm__ volatile("s_waitcnt lgkmcnt(0)\n\ts_barrier" ::: "memory");
    const float* sp = s_part[t & 1];
    float4 p0 = *(const float4*)(sp + 0);
    float4 p1 = *(const float4*)(sp + 4);
    float4 p2 = *(const float4*)(sp + 8);
    float4 p3 = *(const float4*)(sp + 12);
    S = ((p0.x + p0.y) + (p0.z + p0.w)) + ((p1.x + p1.y) + (p1.z + p1.w)) +
        ((p2.x + p2.y) + (p2.z + p2.w)) + ((p3.x + p3.y) + (p3.z + p3.w));
  }

  // logits[b,o] = sum_j cnt[b,j] * Wout[j,o]
  float lg[OO];
#pragma unroll
  for (int o = 0; o < OO; ++o) lg[o] = cnt * Wout[(size_t)tid * OO + o];
#pragma unroll
  for (int o = 0; o < OO; ++o) {
    float v = lg[o];
#pragma unroll
    for (int d = 32; d > 0; d >>= 1) v += __shfl_down(v, d, 64);
    if (lane == 0) s_log[wave][o] = v;
  }
  __syncthreads();
  if (tid < OO) {
    float v = 0.0f;
#pragma unroll
    for (int w = 0; w < 16; ++w) v += s_log[w][tid];
    logits[(size_t)b * OO + tid] = v;
  }
}

extern "C" void kernel_launch(void* const* d_in, const int* in_sizes, int n_in,
                              void* d_out, int out_size, void* d_ws,
                              size_t ws_size, hipStream_t stream) {
  const float* X    = (const float*)d_in[0];  // input_spikes [200][256][784]
  const float* Win  = (const float*)d_in[1];  // [784][1024]
  // d_in[2] = W_rec — unused (exact closed form)
  const float* Wout = (const float*)d_in[3];  // [1024][10]

  float* logits = (float*)d_out;              // [256][10]
  float* hid    = (float*)d_out + BB * OO;    // [200][256][1024]

  dim3 g1(NN / 128, TT * BB / 128);           // 8 x 400 blocks
  gemm_net<<<g1, 256, 0, stream>>>(X, Win, hid);
  snn_scan<<<BB, 1024, 0, stream>>>(hid, Wout, logits);
}